// Round 1
// baseline (303.115 us; speedup 1.0000x reference)
//
#include <hip/hip_runtime.h>

// MyCrossAttention fused kernel for MI355X (gfx950).
// B=4, C=128, T=400, F=64, H=4, HID=CV=32, N=B*T=1600.
// One block per n; 4 waves as 2x2 tile grid over [128 rows][128 cols=s*64+f].

typedef short s8v __attribute__((ext_vector_type(8)));   // 8 bf16 (bit pattern in shorts)
typedef float f4v __attribute__((ext_vector_type(4)));   // MFMA accumulator

__device__ __forceinline__ unsigned short f2bf(float x){
  unsigned u = __float_as_uint(x);
  return (unsigned short)((u + 0x7FFFu + ((u >> 16) & 1u)) >> 16);  // RNE
}
__device__ __forceinline__ float b2f(unsigned short b){
  return __uint_as_float(((unsigned)b) << 16);
}
__device__ __forceinline__ float wred(float v){
  #pragma unroll
  for (int off = 32; off; off >>= 1) v += __shfl_xor(v, off, 64);
  return v;
}

// ---------------- prep: convert weights / (g,z) to bf16 in ws ----------------
__global__ __launch_bounds__(256)
void prep_k(const float* __restrict__ Wq, const float* __restrict__ Wk,
            const float* __restrict__ Wv, const float* __restrict__ Wo,
            const float* __restrict__ gq, const float* __restrict__ zq,
            const float* __restrict__ gk, const float* __restrict__ zk,
            const float* __restrict__ gv, const float* __restrict__ zv,
            const float* __restrict__ go, const float* __restrict__ zo,
            unsigned short* __restrict__ Wb, unsigned* __restrict__ GZ)
{
  int t = blockIdx.x * 256 + threadIdx.x;
  if (t < 65536) {                       // 4 x [128][128] weight matrices
    int sel = t >> 14, i = t & 16383;
    const float* s = sel == 0 ? Wq : sel == 1 ? Wk : sel == 2 ? Wv : Wo;
    Wb[t] = f2bf(s[i]);
  } else {                               // 4 x [128][64] packed (g,z)
    int u = t - 65536;
    int sel = u >> 13, i = u & 8191;
    const float* g = sel == 0 ? gq : sel == 1 ? gk : sel == 2 ? gv : go;
    const float* z = sel == 0 ? zq : sel == 1 ? zk : sel == 2 ? zv : zo;
    GZ[u] = (unsigned)f2bf(g[i]) | ((unsigned)f2bf(z[i]) << 16);
  }
}

// ---------------- 128x128x128 GEMM tile: acc = A(global bf16) * B(LDS) ----------------
// A: row-major [128][128] bf16 bits. B(LDS): rows indexed by output col, elements = k,
// XOR-swizzled: elem_idx = k ^ ((row&7)<<3).
__device__ __forceinline__ void gemm_tile(const unsigned short* __restrict__ A,
                                          const unsigned short* __restrict__ Bl,
                                          int m0, int n0, int row16, int q4,
                                          f4v acc[4][4])
{
  #pragma unroll
  for (int mi = 0; mi < 4; ++mi)
    #pragma unroll
    for (int ni = 0; ni < 4; ++ni)
      acc[mi][ni] = (f4v){0.f, 0.f, 0.f, 0.f};

  #pragma unroll
  for (int kk = 0; kk < 4; ++kk) {
    s8v a[4];
    #pragma unroll
    for (int mi = 0; mi < 4; ++mi)
      a[mi] = *(const s8v*)(A + (m0 + mi*16 + row16)*128 + kk*32 + q4*8);
    #pragma unroll
    for (int ni = 0; ni < 4; ++ni) {
      int rw = n0 + ni*16 + row16;
      const s8v b = *(const s8v*)(Bl + rw*128 + ((kk*32 + q4*8) ^ ((rw & 7) << 3)));
      #pragma unroll
      for (int mi = 0; mi < 4; ++mi)
        acc[mi][ni] = __builtin_amdgcn_mfma_f32_16x16x32_bf16(a[mi], b, acc[mi][ni], 0, 0, 0);
    }
  }
}

// ---------------- QKV epilogue: bias + PReLU + LN(2048) + g/z; write LDS or keep ----------------
__device__ __forceinline__ void qkv_epi(f4v acc[4][4],
                                        const float* __restrict__ bias,
                                        const float* __restrict__ prelu,
                                        const unsigned* __restrict__ GZb,
                                        unsigned short* __restrict__ Lout, bool keep,
                                        int m0, int n0, int row16, int q4, int wm)
{
  float p0 = prelu[2*wm], p1 = prelu[2*wm + 1];
  float sum0 = 0.f, sum1 = 0.f, sq0 = 0.f, sq1 = 0.f;
  #pragma unroll
  for (int mi = 0; mi < 4; ++mi) {
    float ph = (mi < 2) ? p0 : p1;
    #pragma unroll
    for (int j = 0; j < 4; ++j) {
      float bb = bias[m0 + mi*16 + q4*4 + j];
      #pragma unroll
      for (int ni = 0; ni < 4; ++ni) {
        float v = acc[mi][ni][j] + bb;
        v = v >= 0.f ? v : ph * v;
        acc[mi][ni][j] = v;
        if (mi < 2) { sum0 += v; sq0 += v*v; } else { sum1 += v; sq1 += v*v; }
      }
    }
  }
  sum0 = wred(sum0); sq0 = wred(sq0); sum1 = wred(sum1); sq1 = wred(sq1);
  float mu0 = sum0 * (1.f/2048.f), mu1 = sum1 * (1.f/2048.f);
  float rs0 = rsqrtf(sq0 * (1.f/2048.f) - mu0*mu0 + 1e-5f);
  float rs1 = rsqrtf(sq1 * (1.f/2048.f) - mu1*mu1 + 1e-5f);
  #pragma unroll
  for (int mi = 0; mi < 4; ++mi) {
    float mu = (mi < 2) ? mu0 : mu1, rs = (mi < 2) ? rs0 : rs1;
    #pragma unroll
    for (int ni = 0; ni < 4; ++ni) {
      int f = ni*16 + row16;
      int col = n0 + f;
      int sw = (col & 7) << 3;
      #pragma unroll
      for (int j = 0; j < 4; ++j) {
        int r = m0 + mi*16 + q4*4 + j;
        unsigned gz = GZb[r*64 + f];
        float g = b2f((unsigned short)(gz & 0xffffu));
        float z = b2f((unsigned short)(gz >> 16));
        float vn = (acc[mi][ni][j] - mu) * rs * g + z;
        if (keep) acc[mi][ni][j] = vn;
        else      Lout[col*128 + (r ^ sw)] = f2bf(vn);
      }
    }
  }
}

// ---------------- main fused kernel ----------------
__global__ __launch_bounds__(256, 2)
void fused_k(const float* __restrict__ x1, const float* __restrict__ x2,
             const unsigned short* __restrict__ Wb, const unsigned* __restrict__ GZ,
             const float* __restrict__ bq, const float* __restrict__ bk,
             const float* __restrict__ bv, const float* __restrict__ bo,
             const float* __restrict__ pq, const float* __restrict__ pk,
             const float* __restrict__ pv, const float* __restrict__ po,
             float* __restrict__ out)
{
  __shared__ unsigned short Xl[16384];  // x, transposed [col=s*64+f][c], swizzled
  __shared__ unsigned short Kl[16384];  // K, then V, then O (reused)
  __shared__ float sc[16];              // raw scores [h][s][t]
  __shared__ float lnb[8];              // out-LN cross-wave partials

  const int n   = blockIdx.x;
  const int bI  = n / 400, tI = n % 400;
  const int tid = threadIdx.x;
  const int lane = tid & 63, wave = tid >> 6;
  const int wm = wave >> 1, wn = wave & 1;
  const int m0 = wm * 64, n0 = wn * 64;
  const int row16 = lane & 15, q4 = lane >> 4;

  // ---- phase 1: load x -> Xl (bf16, transposed, swizzled) ----
  {
    int c = tid & 127, s = tid >> 7;
    const float* src = (s ? x2 : x1) + ((size_t)(bI*128 + c)*400 + tI)*64;
    #pragma unroll
    for (int j = 0; j < 16; ++j) {
      float4 v = ((const float4*)src)[j];
      int f0 = j * 4;
      float vv[4] = {v.x, v.y, v.z, v.w};
      #pragma unroll
      for (int e = 0; e < 4; ++e) {
        int rw = s*64 + f0 + e;
        Xl[rw*128 + (c ^ ((rw & 7) << 3))] = f2bf(vv[e]);
      }
    }
  }
  __syncthreads();

  f4v acc[4][4];

  // ---- phase 2: K branch -> Kl ----
  gemm_tile(Wb + 16384*1, Xl, m0, n0, row16, q4, acc);
  qkv_epi(acc, bk, pk, GZ + 8192*1, Kl, false, m0, n0, row16, q4, wm);
  __syncthreads();

  // ---- phase 3: Q branch (kept in regs) + scores ----
  gemm_tile(Wb + 16384*0, Xl, m0, n0, row16, q4, acc);
  qkv_epi(acc, bq, pq, GZ + 8192*0, Kl, true, m0, n0, row16, q4, wm);
  {
    float p00 = 0.f, p01 = 0.f, p10 = 0.f, p11 = 0.f;
    #pragma unroll
    for (int mi = 0; mi < 4; ++mi)
      #pragma unroll
      for (int ni = 0; ni < 4; ++ni) {
        int f = ni*16 + row16;
        int sw = (f & 7) << 3;
        #pragma unroll
        for (int j = 0; j < 4; ++j) {
          int r = m0 + mi*16 + q4*4 + j;
          float qv = acc[mi][ni][j];
          float k0 = b2f(Kl[f*128        + (r ^ sw)]);
          float k1 = b2f(Kl[(64+f)*128   + (r ^ sw)]);
          if (mi < 2) { p00 += qv*k0; p01 += qv*k1; }
          else        { p10 += qv*k0; p11 += qv*k1; }
        }
      }
    p00 = wred(p00); p01 = wred(p01); p10 = wred(p10); p11 = wred(p11);
    if (lane == 0) {
      sc[(2*wm + 0)*4 + wn*2 + 0] = p00;
      sc[(2*wm + 0)*4 + wn*2 + 1] = p01;
      sc[(2*wm + 1)*4 + wn*2 + 0] = p10;
      sc[(2*wm + 1)*4 + wn*2 + 1] = p11;
    }
  }
  __syncthreads();

  // ---- phase 4: V branch -> Kl (K is dead) ----
  gemm_tile(Wb + 16384*2, Xl, m0, n0, row16, q4, acc);
  qkv_epi(acc, bv, pv, GZ + 8192*2, Kl, false, m0, n0, row16, q4, wm);
  __syncthreads();

  // ---- phase 5: softmax + 2x2 attention mix, in place in Kl ----
  {
    const float is = 0.02209708691f;  // 1/sqrt(2048)
    #pragma unroll
    for (int i = 0; i < 4; ++i) {
      int g  = tid + 256*i;           // 1024 groups: [f in 64][cgroup in 16]
      int f  = g >> 4, cg = g & 15, c0 = cg*8, h = cg >> 2;
      float s00 = sc[h*4+0]*is, s01 = sc[h*4+1]*is;
      float s10 = sc[h*4+2]*is, s11 = sc[h*4+3]*is;
      float mA = fmaxf(s00, s01), e0 = __expf(s00-mA), e1 = __expf(s01-mA);
      float a00 = e0/(e0+e1), a01 = e1/(e0+e1);
      float mB = fmaxf(s10, s11), e2 = __expf(s10-mB), e3 = __expf(s11-mB);
      float a10 = e2/(e2+e3), a11 = e3/(e2+e3);
      int sw = (f & 7) << 3;          // (64+f)&7 == f&7
      int off0 = f*128      + (c0 ^ sw);
      int off1 = (64+f)*128 + (c0 ^ sw);
      s8v v0 = *(const s8v*)(Kl + off0);
      s8v v1 = *(const s8v*)(Kl + off1);
      s8v o0, o1;
      #pragma unroll
      for (int e = 0; e < 8; ++e) {
        float x0 = b2f((unsigned short)v0[e]);
        float x1v = b2f((unsigned short)v1[e]);
        o0[e] = (short)f2bf(a00*x0 + a01*x1v);
        o1[e] = (short)f2bf(a10*x0 + a11*x1v);
      }
      *(s8v*)(Kl + off0) = o0;
      *(s8v*)(Kl + off1) = o1;
    }
  }
  __syncthreads();

  // ---- phase 6: output projection + LN(8192) + g/z + residual + store ----
  gemm_tile(Wb + 16384*3, Kl, m0, n0, row16, q4, acc);
  {
    float pov = po[0];
    float sum = 0.f, sq = 0.f;
    #pragma unroll
    for (int mi = 0; mi < 4; ++mi)
      #pragma unroll
      for (int j = 0; j < 4; ++j) {
        float bb = bo[m0 + mi*16 + q4*4 + j];
        #pragma unroll
        for (int ni = 0; ni < 4; ++ni) {
          float v = acc[mi][ni][j] + bb;
          v = v >= 0.f ? v : pov * v;
          acc[mi][ni][j] = v;
          sum += v; sq += v*v;
        }
      }
    sum = wred(sum); sq = wred(sq);
    if (lane == 0) { lnb[wave] = sum; lnb[4 + wave] = sq; }
    __syncthreads();
    float tot  = lnb[wn]     + lnb[2 + wn];
    float totq = lnb[4 + wn] + lnb[6 + wn];
    float mu = tot * (1.f/8192.f);
    float rs = rsqrtf(totq * (1.f/8192.f) - mu*mu + 1e-5f);
    const unsigned* GZo = GZ + 8192*3;
    float* outs = out + (size_t)wn * 13107200u;  // s = wn selects y1/y2
    #pragma unroll
    for (int mi = 0; mi < 4; ++mi)
      #pragma unroll
      for (int ni = 0; ni < 4; ++ni) {
        int f = ni*16 + row16;
        int col = n0 + f;
        int sw = (col & 7) << 3;
        #pragma unroll
        for (int j = 0; j < 4; ++j) {
          int r = m0 + mi*16 + q4*4 + j;
          unsigned gz = GZo[r*64 + f];
          float g = b2f((unsigned short)(gz & 0xffffu));
          float z = b2f((unsigned short)(gz >> 16));
          float y  = (acc[mi][ni][j] - mu) * rs * g + z;
          float xv = b2f(Xl[col*128 + (r ^ sw)]);   // residual (bf16-rounded x)
          outs[((size_t)(bI*128 + r)*400 + tI)*64 + f] = y + xv;
        }
      }
  }
}

extern "C" void kernel_launch(void* const* d_in, const int* in_sizes, int n_in,
                              void* d_out, int out_size, void* d_ws, size_t ws_size,
                              hipStream_t stream)
{
  (void)in_sizes; (void)n_in; (void)out_size; (void)ws_size;
  const float* x1 = (const float*)d_in[0];
  const float* x2 = (const float*)d_in[1];
  const float* Wq = (const float*)d_in[2];
  const float* bq = (const float*)d_in[3];
  const float* pq = (const float*)d_in[4];
  const float* gq = (const float*)d_in[5];
  const float* zq = (const float*)d_in[6];
  const float* Wk = (const float*)d_in[7];
  const float* bk = (const float*)d_in[8];
  const float* pk = (const float*)d_in[9];
  const float* gk = (const float*)d_in[10];
  const float* zk = (const float*)d_in[11];
  const float* Wv = (const float*)d_in[12];
  const float* bv = (const float*)d_in[13];
  const float* pv = (const float*)d_in[14];
  const float* gv = (const float*)d_in[15];
  const float* zv = (const float*)d_in[16];
  const float* Wo = (const float*)d_in[17];
  const float* bo = (const float*)d_in[18];
  const float* po = (const float*)d_in[19];
  const float* go = (const float*)d_in[20];
  const float* zo = (const float*)d_in[21];

  unsigned short* Wb = (unsigned short*)d_ws;            // 131072 B
  unsigned*       GZ = (unsigned*)((char*)d_ws + 131072); // 131072 B

  prep_k<<<384, 256, 0, stream>>>(Wq, Wk, Wv, Wo, gq, zq, gk, zk, gv, zv, go, zo, Wb, GZ);
  fused_k<<<1600, 256, 0, stream>>>(x1, x2, Wb, GZ, bq, bk, bv, bo, pq, pk, pv, po,
                                    (float*)d_out);
}

// Round 3
// 236.252 us; speedup vs baseline: 1.2830x; 1.2830x over previous
//
#include <hip/hip_runtime.h>

// MyCrossAttention fused kernel for MI355X (gfx950), round 3.
// B=4, C=128, T=400, F=64, H=4, HID=CV=32, N=B*T=1600.
// One block per n; 8 waves (512 thr) as 4x2 grid over [128 rows][128 cols=s*64+f].
// Per wave: 32 rows (= one head's channels) x 64 cols (= one stream) -> one LN group.
// NOTE: round-1-proven scalar epilogue/score/residual accesses; only the wave
// restructure differs from the passing round-1 kernel.

typedef short s8v __attribute__((ext_vector_type(8)));   // 8 bf16 bits
typedef float f4v __attribute__((ext_vector_type(4)));   // MFMA accumulator

__device__ __forceinline__ unsigned short f2bf(float x){
  unsigned u = __float_as_uint(x);
  return (unsigned short)((u + 0x7FFFu + ((u >> 16) & 1u)) >> 16);  // RNE
}
__device__ __forceinline__ float b2f(unsigned short b){
  return __uint_as_float(((unsigned)b) << 16);
}
__device__ __forceinline__ float wred(float v){
  #pragma unroll
  for (int off = 32; off; off >>= 1) v += __shfl_xor(v, off, 64);
  return v;
}

// ---------------- prep: weights bf16; (g,z) packed bf16 [r][f] (round-1 layout) ----------------
__global__ __launch_bounds__(256)
void prep_k(const float* __restrict__ Wq, const float* __restrict__ Wk,
            const float* __restrict__ Wv, const float* __restrict__ Wo,
            const float* __restrict__ gq, const float* __restrict__ zq,
            const float* __restrict__ gk, const float* __restrict__ zk,
            const float* __restrict__ gv, const float* __restrict__ zv,
            const float* __restrict__ go, const float* __restrict__ zo,
            unsigned short* __restrict__ Wb, unsigned* __restrict__ GZ)
{
  int t = blockIdx.x * 256 + threadIdx.x;
  if (t < 65536) {                       // 4 x [128][128] weight matrices
    int sel = t >> 14, i = t & 16383;
    const float* s = sel == 0 ? Wq : sel == 1 ? Wk : sel == 2 ? Wv : Wo;
    Wb[t] = f2bf(s[i]);
  } else {                               // 4 x [128][64] packed (g,z)
    int u = t - 65536;
    int sel = u >> 13, i = u & 8191;
    const float* g = sel == 0 ? gq : sel == 1 ? gk : sel == 2 ? gv : go;
    const float* z = sel == 0 ? zq : sel == 1 ? zk : sel == 2 ? zv : zo;
    GZ[u] = (unsigned)f2bf(g[i]) | ((unsigned)f2bf(z[i]) << 16);
  }
}

// ---------------- 32x64x128 GEMM tile: acc = A(global bf16) * B(LDS swizzled) ----------------
__device__ __forceinline__ void gemm_tile(const unsigned short* __restrict__ A,
                                          const unsigned short* __restrict__ Bl,
                                          int m0, int n0, int row16, int q4,
                                          f4v acc[2][4])
{
  #pragma unroll
  for (int mi = 0; mi < 2; ++mi)
    #pragma unroll
    for (int ni = 0; ni < 4; ++ni)
      acc[mi][ni] = (f4v){0.f, 0.f, 0.f, 0.f};

  #pragma unroll
  for (int kk = 0; kk < 4; ++kk) {
    s8v a[2];
    #pragma unroll
    for (int mi = 0; mi < 2; ++mi)
      a[mi] = *(const s8v*)(A + (m0 + mi*16 + row16)*128 + kk*32 + q4*8);
    #pragma unroll
    for (int ni = 0; ni < 4; ++ni) {
      int rw = n0 + ni*16 + row16;
      const s8v b = *(const s8v*)(Bl + rw*128 + ((kk*32 + q4*8) ^ ((rw & 7) << 3)));
      #pragma unroll
      for (int mi = 0; mi < 2; ++mi)
        acc[mi][ni] = __builtin_amdgcn_mfma_f32_16x16x32_bf16(a[mi], b, acc[mi][ni], 0, 0, 0);
    }
  }
}

// ---------------- QKV epilogue: bias + PReLU + LN(2048 = wave tile) + g/z (all scalar) ----------------
__device__ __forceinline__ void qkv_epi(f4v acc[2][4],
                                        const float* __restrict__ bias,
                                        float p,
                                        const unsigned* __restrict__ GZb,  // [r][f]
                                        unsigned short* __restrict__ Lout, bool keep,
                                        int m0, int n0, int row16, int q4)
{
  float sum = 0.f, sq = 0.f;
  #pragma unroll
  for (int mi = 0; mi < 2; ++mi) {
    #pragma unroll
    for (int j = 0; j < 4; ++j) {
      float bb = bias[m0 + mi*16 + q4*4 + j];
      #pragma unroll
      for (int ni = 0; ni < 4; ++ni) {
        float v = acc[mi][ni][j] + bb;
        v = v >= 0.f ? v : p * v;
        acc[mi][ni][j] = v;
        sum += v; sq += v*v;
      }
    }
  }
  sum = wred(sum); sq = wred(sq);
  float mu = sum * (1.f/2048.f);
  float rs = rsqrtf(sq * (1.f/2048.f) - mu*mu + 1e-5f);
  #pragma unroll
  for (int mi = 0; mi < 2; ++mi) {
    #pragma unroll
    for (int ni = 0; ni < 4; ++ni) {
      int f   = ni*16 + row16;
      int col = n0 + f;
      int sw  = (col & 7) << 3;
      #pragma unroll
      for (int j = 0; j < 4; ++j) {
        int r = m0 + mi*16 + q4*4 + j;
        unsigned gz = GZb[r*64 + f];
        float g = b2f((unsigned short)(gz & 0xffffu));
        float z = b2f((unsigned short)(gz >> 16));
        float vn = (acc[mi][ni][j] - mu) * rs * g + z;
        if (keep) acc[mi][ni][j] = vn;
        else      Lout[col*128 + (r ^ sw)] = f2bf(vn);
      }
    }
  }
}

// ---------------- main fused kernel ----------------
__global__ __launch_bounds__(512, 4)
void fused_k(const float* __restrict__ x1, const float* __restrict__ x2,
             const unsigned short* __restrict__ Wb, const unsigned* __restrict__ GZ,
             const float* __restrict__ bq, const float* __restrict__ bk,
             const float* __restrict__ bv, const float* __restrict__ bo,
             const float* __restrict__ pq, const float* __restrict__ pk,
             const float* __restrict__ pv, const float* __restrict__ po,
             float* __restrict__ out)
{
  __shared__ unsigned short Xl[16384];  // x, transposed [rw=s*64+f][c], swizzled
  __shared__ unsigned short Kl[16384];  // K, then V/O (reused)
  __shared__ float sc[16];              // raw scores [h][s][t]
  __shared__ float lnb[16];             // out-LN cross-wave partials

  const int n   = blockIdx.x;
  const int bI  = n / 400, tI = n % 400;
  const int tid = threadIdx.x;
  const int lane = tid & 63, wave = tid >> 6;
  const int wm = wave >> 1, wn = wave & 1;     // wm = head (rows), wn = stream (cols)
  const int m0 = wm * 32, n0 = wn * 64;
  const int row16 = lane & 15, q4 = lane >> 4;

  // ---- phase 1: load x -> Xl (bf16, transposed, swizzled) ----
  {
    int c = tid & 127, s = (tid >> 7) & 1, half = tid >> 8;
    const float* src = (s ? x2 : x1) + ((size_t)(bI*128 + c)*400 + tI)*64 + half*32;
    #pragma unroll
    for (int j = 0; j < 8; ++j) {
      float4 v = ((const float4*)src)[j];
      int f0 = half*32 + j*4;
      float vv[4] = {v.x, v.y, v.z, v.w};
      #pragma unroll
      for (int e = 0; e < 4; ++e) {
        int rw = s*64 + f0 + e;
        Xl[rw*128 + (c ^ ((rw & 7) << 3))] = f2bf(vv[e]);
      }
    }
  }
  __syncthreads();

  f4v acc[2][4];

  // ---- phase 2: K branch -> Kl ----
  gemm_tile(Wb + 16384*1, Xl, m0, n0, row16, q4, acc);
  qkv_epi(acc, bk, pk[wm], GZ + 8192*1, Kl, false, m0, n0, row16, q4);
  __syncthreads();

  // ---- phase 3: Q branch (kept in regs) + scores ----
  gemm_tile(Wb + 16384*0, Xl, m0, n0, row16, q4, acc);
  qkv_epi(acc, bq, pq[wm], GZ + 8192*0, Kl, true, m0, n0, row16, q4);
  {
    float p0 = 0.f, p1 = 0.f;   // scores vs K stream t=0,1 for (h=wm, s=wn)
    #pragma unroll
    for (int mi = 0; mi < 2; ++mi) {
      #pragma unroll
      for (int ni = 0; ni < 4; ++ni) {
        int f  = ni*16 + row16;
        int sw = (f & 7) << 3;      // (64+f)&7 == f&7
        #pragma unroll
        for (int j = 0; j < 4; ++j) {
          int r = m0 + mi*16 + q4*4 + j;
          float qv = acc[mi][ni][j];
          float k0 = b2f(Kl[f*128      + (r ^ sw)]);
          float k1 = b2f(Kl[(64+f)*128 + (r ^ sw)]);
          p0 += qv * k0;
          p1 += qv * k1;
        }
      }
    }
    p0 = wred(p0); p1 = wred(p1);
    if (lane == 0) {
      sc[wm*4 + wn*2 + 0] = p0;
      sc[wm*4 + wn*2 + 1] = p1;
    }
  }
  __syncthreads();

  // ---- phase 4: V branch -> Kl (K dead) ----
  gemm_tile(Wb + 16384*2, Xl, m0, n0, row16, q4, acc);
  qkv_epi(acc, bv, pv[wm], GZ + 8192*2, Kl, false, m0, n0, row16, q4);
  __syncthreads();

  // ---- phase 5: softmax + 2x2 attention mix, in place in Kl ----
  {
    const float is = 0.02209708691f;  // 1/sqrt(2048)
    #pragma unroll
    for (int i = 0; i < 2; ++i) {
      int g  = tid + 512*i;           // 1024 groups: [f in 64][cgroup in 16]
      int f  = g >> 4, cg = g & 15, c0 = cg*8, h = cg >> 2;
      float s00 = sc[h*4+0]*is, s01 = sc[h*4+1]*is;
      float s10 = sc[h*4+2]*is, s11 = sc[h*4+3]*is;
      float mA = fmaxf(s00, s01), e0 = __expf(s00-mA), e1 = __expf(s01-mA);
      float a00 = e0/(e0+e1), a01 = e1/(e0+e1);
      float mB = fmaxf(s10, s11), e2 = __expf(s10-mB), e3 = __expf(s11-mB);
      float a10 = e2/(e2+e3), a11 = e3/(e2+e3);
      int sw = (f & 7) << 3;
      int off0 = f*128      + (c0 ^ sw);
      int off1 = (64+f)*128 + (c0 ^ sw);
      s8v v0 = *(const s8v*)(Kl + off0);
      s8v v1 = *(const s8v*)(Kl + off1);
      s8v o0, o1;
      #pragma unroll
      for (int e = 0; e < 8; ++e) {
        float x0  = b2f((unsigned short)v0[e]);
        float x1v = b2f((unsigned short)v1[e]);
        o0[e] = (short)f2bf(a00*x0 + a01*x1v);
        o1[e] = (short)f2bf(a10*x0 + a11*x1v);
      }
      *(s8v*)(Kl + off0) = o0;
      *(s8v*)(Kl + off1) = o1;
    }
  }
  __syncthreads();

  // ---- phase 6: output projection + LN(8192 per stream) + g/z + residual + store ----
  gemm_tile(Wb + 16384*3, Kl, m0, n0, row16, q4, acc);
  {
    float pov = po[0];
    float sum = 0.f, sq = 0.f;
    #pragma unroll
    for (int mi = 0; mi < 2; ++mi) {
      #pragma unroll
      for (int j = 0; j < 4; ++j) {
        float bb = bo[m0 + mi*16 + q4*4 + j];
        #pragma unroll
        for (int ni = 0; ni < 4; ++ni) {
          float v = acc[mi][ni][j] + bb;
          v = v >= 0.f ? v : pov * v;
          acc[mi][ni][j] = v;
          sum += v; sq += v*v;
        }
      }
    }
    sum = wred(sum); sq = wred(sq);
    if (lane == 0) { lnb[wave] = sum; lnb[8 + wave] = sq; }
    __syncthreads();
    float tot  = lnb[wn]   + lnb[wn+2]   + lnb[wn+4]   + lnb[wn+6];
    float totq = lnb[8+wn] + lnb[8+wn+2] + lnb[8+wn+4] + lnb[8+wn+6];
    float mu = tot * (1.f/8192.f);
    float rs = rsqrtf(totq * (1.f/8192.f) - mu*mu + 1e-5f);
    const unsigned* GZo = GZ + 8192*3;
    float* outs = out + (size_t)wn * 13107200u;  // s = wn selects y1/y2
    #pragma unroll
    for (int mi = 0; mi < 2; ++mi) {
      #pragma unroll
      for (int ni = 0; ni < 4; ++ni) {
        int f   = ni*16 + row16;
        int col = n0 + f;
        int sw  = (col & 7) << 3;
        #pragma unroll
        for (int j = 0; j < 4; ++j) {
          int r = m0 + mi*16 + q4*4 + j;
          unsigned gz = GZo[r*64 + f];
          float g = b2f((unsigned short)(gz & 0xffffu));
          float z = b2f((unsigned short)(gz >> 16));
          float y  = (acc[mi][ni][j] - mu) * rs * g + z;
          float xv = b2f(Xl[col*128 + (r ^ sw)]);   // residual (bf16-rounded x)
          outs[((size_t)(bI*128 + r)*400 + tI)*64 + f] = y + xv;
        }
      }
    }
  }
}

extern "C" void kernel_launch(void* const* d_in, const int* in_sizes, int n_in,
                              void* d_out, int out_size, void* d_ws, size_t ws_size,
                              hipStream_t stream)
{
  (void)in_sizes; (void)n_in; (void)out_size; (void)ws_size;
  const float* x1 = (const float*)d_in[0];
  const float* x2 = (const float*)d_in[1];
  const float* Wq = (const float*)d_in[2];
  const float* bq = (const float*)d_in[3];
  const float* pq = (const float*)d_in[4];
  const float* gq = (const float*)d_in[5];
  const float* zq = (const float*)d_in[6];
  const float* Wk = (const float*)d_in[7];
  const float* bk = (const float*)d_in[8];
  const float* pk = (const float*)d_in[9];
  const float* gk = (const float*)d_in[10];
  const float* zk = (const float*)d_in[11];
  const float* Wv = (const float*)d_in[12];
  const float* bv = (const float*)d_in[13];
  const float* pv = (const float*)d_in[14];
  const float* gv = (const float*)d_in[15];
  const float* zv = (const float*)d_in[16];
  const float* Wo = (const float*)d_in[17];
  const float* bo = (const float*)d_in[18];
  const float* po = (const float*)d_in[19];
  const float* go = (const float*)d_in[20];
  const float* zo = (const float*)d_in[21];

  unsigned short* Wb = (unsigned short*)d_ws;             // 131072 B
  unsigned*       GZ = (unsigned*)((char*)d_ws + 131072); // 131072 B

  prep_k<<<384, 256, 0, stream>>>(Wq, Wk, Wv, Wo, gq, zq, gk, zk, gv, zv, go, zo, Wb, GZ);
  fused_k<<<1600, 512, 0, stream>>>(x1, x2, Wb, GZ, bq, bk, bv, bo, pq, pk, pv, po,
                                    (float*)d_out);
}